// Round 18
// baseline (128.335 us; speedup 1.0000x reference)
//
#include <hip/hip_runtime.h>
#include <math.h>

// EvidNets R32: R31 + __launch_bounds__(512, 2) — declare the TRUE occupancy
// (2 waves/EU, LDS-bound) to raise the VGPR budget 128 -> 256.
//   A_c(b) = prod_k (1 - s_kb*(1-U_kc)),  N(b) = prod_k (1 - s_kb)
//   out[b][c<20] = (A_c-N)/K, out[b][20] = N/K, K = sum_c A_c - 19N
//   s_kb = alphap_k * exp(-gamma_k^2*(0.5*(|W_k|^2+|x_b|^2) - W_k.x_b))
// R31 post-mortem: register cuts worked (kernel 121->62.6, scratch
// 154->104MB) but VGPR pinned at 128 WITH spills. New mechanism: 128 is the
// allocator's DEFAULT target (4 waves/EU) for 512-thr kernels, not a HW
// bound — this kernel is LDS-bound (152KB) to 1 block/CU = 2 waves/SIMD,
// where 256 VGPRs/wave are legal (m69: occupancy halves at 64/128/256).
// __launch_bounds__(512, 2) declares exactly that -> budget 256 >= ~140
// live. (R4/R8's min-waves spills were min-waves set HIGH = tightening;
// 2 loosens.) Single-variable change on the otherwise-verified R31.
// Fill-accounting theory (R28/R30): workspace-free single-dispatch rounds
// pay NO 43us poison-fill; overhead 12-17us. Non-spilling ~50us kernel ->
// dur ~60-75 vs best 97.7 (R29). R31's odd 65us overhead is plausibly the
// ~100MB scratch footprint's per-iteration cost — vanishes with the spill.
// FINAL tripwires: VGPR still 128 + scratch -> revert R29 + declare;
// clean but dur > 100 -> revert R29 + declare.

#define NBATCH 16384
#define ND     256
#define NP     512
#define NCLS   20
#define OC     21

typedef short  short8  __attribute__((ext_vector_type(8)));
typedef short  short4v __attribute__((ext_vector_type(4)));
typedef float  f32x16  __attribute__((ext_vector_type(16)));

__device__ __forceinline__ unsigned short f2bf_rn(float f) {
  unsigned int u = __float_as_uint(f);
  unsigned int r = (u + 0x7FFFu + ((u >> 16) & 1u)) >> 16;   // RNE (finite inputs)
  return (unsigned short)r;
}
__device__ __forceinline__ float bf2f(unsigned short h) {
  return __uint_as_float(((unsigned int)h) << 16);
}

// One MFMA pass over sample-half sh vs one 32-proto tile, streaming RAW W
// with inline hi/lo bf16 split. K=256, ONE acc chain, depth-4 float4 ring.
// WQCOMP: accumulate |W_row|^2 during the stream (full row via shfl 32).
// Epilogue writes the swizzled s-band directly (no sreg materialization).
template<bool WQCOMP>
__device__ __forceinline__ void mfma_pass_w(
    const short* __restrict__ Ah, const short* __restrict__ Al,
    const float* __restrict__ bp,   // Wm + (tile*32 + (lane&31))*256 + (lane>>5)*8
    const int lane, const int sh, const float* __restrict__ xqs,
    float& wq, const float apk, const float g2k,
    float* __restrict__ sc, const int p)
{
  float4 r0[4], r1[4];
  #pragma unroll
  for (int q = 0; q < 4; ++q) {
    r0[q] = *(const float4*)(bp + q * 16);
    r1[q] = *(const float4*)(bp + q * 16 + 4);
  }

  f32x16 acc;
  #pragma unroll
  for (int i = 0; i < 16; ++i) acc[i] = 0.f;
  const short8* aH = (const short8*)Ah + (size_t)sh * 1024 + lane;
  const short8* aL = (const short8*)Al + (size_t)sh * 1024 + lane;
  float ssq = 0.f;
  #pragma unroll
  for (int step = 0; step < 16; ++step) {
    const int slot = step & 3;
    const float4 f0 = r0[slot], f1 = r1[slot];
    if (step < 12) {
      r0[slot] = *(const float4*)(bp + (step + 4) * 16);
      r1[slot] = *(const float4*)(bp + (step + 4) * 16 + 4);
    }
    const short8 ah = aH[step * 64], al = aL[step * 64];
    const float v[8] = {f0.x, f0.y, f0.z, f0.w, f1.x, f1.y, f1.z, f1.w};
    short8 bh, bl;
    #pragma unroll
    for (int j = 0; j < 8; ++j) {
      if (WQCOMP) ssq = fmaf(v[j], v[j], ssq);
      const unsigned short hh = f2bf_rn(v[j]);
      bh[j] = (short)hh;
      bl[j] = (short)f2bf_rn(v[j] - bf2f(hh));
    }
    acc = __builtin_amdgcn_mfma_f32_32x32x16_bf16(ah, bh, acc, 0, 0, 0);
    acc = __builtin_amdgcn_mfma_f32_32x32x16_bf16(ah, bl, acc, 0, 0, 0);
    acc = __builtin_amdgcn_mfma_f32_32x32x16_bf16(al, bh, acc, 0, 0, 0);
  }
  if (WQCOMP) {                        // lane l: row (l&31), half (l>>5)
    ssq += __shfl_xor(ssq, 32, 64);    // pair l/l^32 = same row, other half
    wq = ssq;
  }
  // C/D: col(n)=lane&31 (proto), row(m)=(rg&3)+8*(rg>>2)+4*(lane>>5)
  const int h = lane >> 5;
  #pragma unroll
  for (int rg = 0; rg < 16; ++rg) {
    const int   m  = (rg & 3) + 8 * (rg >> 2) + 4 * h;
    const int   b  = sh * 32 + m;
    const float dv = 0.5f * (wq + xqs[b]) - acc[rg];
    sc[b * 256 + ((p + 4 * b) & 255)] = apk * __expf(-g2k * dv);
  }
}

// ---- single kernel: 256 blocks x 512 thr (1 block/CU). Block bx: samples
// bx*64..+64, ALL 512 protos in two phases; wave wv owns tile (ph*8+wv).
// Barrier-free middle (wave-private s-bands + vsl). LDS: A-frags 64KB +
// sc[64][256] 64KB + vsl 20KB + xqs; endgame aliases A after B5.
// __launch_bounds__(512, 2): min 2 waves/EU == true (LDS-bound) occupancy
// -> 256-VGPR budget; default (4 waves/EU -> 128) spilled in R30/R31. ----
__global__ __launch_bounds__(512, 2)
void evid_one(const float* __restrict__ X,    const float* __restrict__ Wm,
              const float* __restrict__ BETA, const float* __restrict__ ALPHA,
              const float* __restrict__ GAMMA, float* __restrict__ OUT)
{
  __shared__ __align__(16) char pool[131072];
  __shared__ float vsl[8 * NCLS * 32];   // per-wave private VS slices (20KB)
  __shared__ float xqs[64];
  short* Ah = (short*)pool;            // 16384 shorts = 32KB
  short* Al = (short*)(pool + 32768);  // 16384 shorts = 32KB
  float* sc = (float*)(pool + 65536);  // 64 x 256 floats = 64KB (per phase)

  const int t    = threadIdx.x;
  const int lane = t & 63;
  const int wv   = __builtin_amdgcn_readfirstlane(t >> 6);  // wave 0..7
  const int bx   = blockIdx.x;
  const int bbase = bx * 64;
  const int pl = lane & 31, h = lane >> 5;

  // ---- stage: 64 X rows f32 -> hi/lo bf16 fragments (8 lanes/row, once) ----
  {
    const int r  = t >> 3;
    const int sg = t & 7;
    const int rsh = r >> 5, rm = r & 31;
    const float* xrow = X + (size_t)(bbase + r) * ND;
    float ssq = 0.f;
    #pragma unroll
    for (int it = 0; it < 8; ++it) {
      const int c0 = it * 32 + sg * 4;
      const float4 v = *(const float4*)(xrow + c0);
      const float vv[4] = {v.x, v.y, v.z, v.w};
      short4v h4, l4;
      #pragma unroll
      for (int j = 0; j < 4; ++j) {
        ssq = fmaf(vv[j], vv[j], ssq);
        const unsigned short hh = f2bf_rn(vv[j]);
        h4[j] = (short)hh;
        l4[j] = (short)f2bf_rn(vv[j] - bf2f(hh));
      }
      const int step = c0 >> 4, hf = (c0 >> 3) & 1, j0 = c0 & 7;
      const int base = (((rsh * 16 + step) * 64) + (rm + 32 * hf)) * 8 + j0;
      *(short4v*)&Ah[base] = h4;
      *(short4v*)&Al[base] = l4;
    }
    ssq += __shfl_xor(ssq, 1, 64);
    ssq += __shfl_xor(ssq, 2, 64);
    ssq += __shfl_xor(ssq, 4, 64);
    if (sg == 0) xqs[r] = ssq;
  }
  __syncthreads();                     // B1: A-frags + xqs ready

  float Apc[OC];
  #pragma unroll
  for (int c = 0; c < OC; ++c) Apc[c] = 1.0f;

  float* vw = vsl + wv * (NCLS * 32);  // this wave's private VS slice

  // ---- two proto-half phases; wave wv owns tile (ph*8 + wv). NO barriers:
  // s-band + vsl are wave-private; same-wave LDS ops execute in order. ----
  #pragma unroll
  for (int ph = 0; ph < 2; ++ph) {
    const int p0 = ph * 256 + wv * 32;                // phase proto base

    // -- VS slice from BETA: lane (h,pl) -> proto p0+pl, classes h*10..+10 --
    {
      const float* brow = BETA + (size_t)(p0 + pl) * NCLS + h * 10;
      float b[10];
      #pragma unroll
      for (int q = 0; q < 10; ++q) b[q] = brow[q];
      float bs = 0.f;
      #pragma unroll
      for (int q = 0; q < 10; ++q) bs = fmaf(b[q], b[q], bs);
      bs += __shfl_xor(bs, 32, 64);                   // full 20-class sum
      const float binv = 1.f / bs;
      #pragma unroll
      for (int q = 0; q < 10; ++q)
        vw[(h * 10 + q) * 32 + pl] = 1.f - b[q] * b[q] * binv;
    }

    // -- per-lane proto params inline --
    const int kp = p0 + pl;
    const float apk = 0.99f / (1.f + __expf(-ALPHA[kp]));
    const float gk  = GAMMA[kp];
    const float g2k = gk * gk;

    // -- raw-W stream base for this wave's tile --
    const float* bp = Wm + ((size_t)(ph * 8 + wv) * 32 + pl) * ND + h * 8;
    const int p = wv * 32 + pl;                       // proto within phase

    float wq;
    mfma_pass_w<true >(Ah, Al, bp, lane, 0, xqs, wq, apk, g2k, sc, p);
    mfma_pass_w<false>(Ah, Al, bp, lane, 1, xqs, wq, apk, g2k, sc, p);
    // no barrier: within-wave LDS write->read ordering via lgkmcnt

    // ---- combine (R21 verbatim): thread b = lane, own k-slice (wv) ----
    {
      float sv[32];
      const int c0 = (wv * 32 + 4 * lane);
      #pragma unroll
      for (int q = 0; q < 8; ++q)
        *(float4*)&sv[4 * q] = *(const float4*)&sc[lane * 256 + ((c0 + 4 * q) & 255)];

      #pragma unroll 4
      for (int c = 0; c < NCLS; ++c) {
        const float* vp = vw + c * 32;                // LDS broadcast reads
        float f8[8];
        #pragma unroll
        for (int j = 0; j < 8; ++j) f8[j] = fmaf(-sv[j], vp[j], 1.0f);
        #pragma unroll
        for (int j = 8; j < 32; ++j) f8[j & 7] *= fmaf(-sv[j], vp[j], 1.0f);
        Apc[c] *= ((f8[0] * f8[1]) * (f8[2] * f8[3])) *
                  ((f8[4] * f8[5]) * (f8[6] * f8[7]));
      }
      // c = 20: VS row == 1.0 -> f = 1 - s
      {
        float f8[8];
        #pragma unroll
        for (int j = 0; j < 8; ++j) f8[j] = 1.0f - sv[j];
        #pragma unroll
        for (int j = 8; j < 32; ++j) f8[j & 7] *= (1.0f - sv[j]);
        Apc[NCLS] *= ((f8[0] * f8[1]) * (f8[2] * f8[3])) *
                     ((f8[4] * f8[5]) * (f8[6] * f8[7]));
      }
    }
  }
  __syncthreads();                     // B5: all waves done with A/sc regions

  // ---- endgame: reduce 8 wave-partials, normalize, store OUT in-block ----
  float* E  = (float*)pool;            // 8*21*64 floats = 42KB (A region, dead)
  float* R  = (float*)(pool + 43008);  // 21*64 floats
  float* kv = (float*)(pool + 48384);  // 64 floats
  #pragma unroll
  for (int c = 0; c < OC; ++c) E[(wv * OC + c) * 64 + lane] = Apc[c];
  __syncthreads();
  {
    const int b = t & 63, j = t >> 6;
    for (int c = j; c < OC; c += 8) {
      float p = E[c * 64 + b];
      #pragma unroll
      for (int w = 1; w < 8; ++w) p *= E[(w * OC + c) * 64 + b];
      R[c * 64 + b] = p;
    }
  }
  __syncthreads();
  if (t < 64) {
    const float Nv = R[NCLS * 64 + t];
    float K = Nv;
    #pragma unroll
    for (int c = 0; c < NCLS; ++c) K += R[c * 64 + t] - Nv;
    kv[t] = 1.0f / K;
  }
  __syncthreads();
  for (int idx = t; idx < 64 * OC; idx += 512) {
    const int b = idx / OC, c = idx - b * OC;
    const float Nv = R[NCLS * 64 + b];
    const float ik = kv[b];
    OUT[(size_t)bx * 64 * OC + idx] = (c < NCLS) ? (R[c * 64 + b] - Nv) * ik : Nv * ik;
  }
}

extern "C" void kernel_launch(void* const* d_in, const int* in_sizes, int n_in,
                              void* d_out, int out_size, void* d_ws, size_t ws_size,
                              hipStream_t stream) {
  (void)in_sizes; (void)n_in; (void)out_size; (void)d_ws; (void)ws_size;
  const float* X     = (const float*)d_in[0];
  const float* Wm    = (const float*)d_in[1];
  const float* BETA  = (const float*)d_in[2];
  const float* ALPHA = (const float*)d_in[3];
  const float* GAMMA = (const float*)d_in[4];
  float* OUT = (float*)d_out;

  hipLaunchKernelGGL(evid_one, dim3(NBATCH / 64), dim3(512), 0, stream,
                     X, Wm, BETA, ALPHA, GAMMA, OUT);
}

// Round 19
// 96.833 us; speedup vs baseline: 1.3253x; 1.3253x over previous
//
#include <hip/hip_runtime.h>
#include <math.h>

// EvidNets R33 == R29 == R21 (FINAL, reverted per pre-committed tripwire):
// best measured kernel of the campaign, 97.9/97.7us across two runs.
//   A_c(b) = prod_k (1 - s_kb*(1-U_kc)),  N(b) = prod_k (1 - s_kb)
//   out[b][c<20] = (A_c-N)/K, out[b][20] = N/K, K = sum_c A_c - 19N
//   s_kb = alphap_k * exp(-gamma_k^2*(0.5*(|W_k|^2+|x_b|^2) - W_k.x_b))
// Campaign close-out (R15-R32), all measured on-device:
//  - 1024-thr blocks: DEAD (R15/R23/R24: hard 64-VGPR allocator cap).
//  - 512-thr fused (needs ~140 live): DEAD (R28/R30/R31/R32: hard 128 cap;
//    waves_per_eu x2 AND launch_bounds min-waves at 1024/4 AND 512/2 all
//    ignored -> permanent scratch spill). The fill-free single-dispatch
//    path (~25us prize: no 43us workspace poison-fill charge) is thereby
//    unreachable on this toolchain.
//  - cross-block handoff: DEAD (R16/R17: agent-scope fence = serialized
//    L2 writeback/invalidate across non-coherent XCDs, 4x slowdown).
//  - 32-sample tiles: worse (R18b/R22/R25/R26: B-traffic x2 / VST stream).
//  - barrier removal (R20) + VS->LDS staging (R21): the two real wins,
//    100.7 -> 97.9.
// Final decomposition of 97.7us: 43 harness fill (charged when d_ws used) +
// ~4 prep + ~45 evid64 (latency-bound at 2 waves/SIMD; ~18us issue-floor
// work; every occupancy/tiling lever measured worse) + ~6 gaps.
// Structure: two dispatches (prep + evid64), 256 blocks x 512 thr
// (1 block/CU), block = 64 samples x ALL 512 protos in two phases, wave wv
// owns tile (ph*8+wv). Barrier-free middle (wave-private s-bands + VS
// slices). VS staged to LDS per wave-phase (hidden under MFMA). Depth-8
// B ring. Full product, normalize, OUT in-block.

#define NBATCH 16384
#define ND     256
#define NP     512
#define NCLS   20
#define OC     21

typedef short  short8  __attribute__((ext_vector_type(8)));
typedef short  short4v __attribute__((ext_vector_type(4)));
typedef unsigned short ushort8 __attribute__((ext_vector_type(8)));
typedef float  f32x16  __attribute__((ext_vector_type(16)));

// ---- workspace layout (bytes) ----
#define OFF_PWH 0u
#define OFF_PWL 262144u
#define OFF_VS  524288u                 // float VS[21][512] = 1-U (row 20 = 1)
#define OFF_WQ  567296u
#define OFF_AP  569344u
#define OFF_G2  571392u

__device__ __forceinline__ unsigned short f2bf_rn(float f) {
  unsigned int u = __float_as_uint(f);
  unsigned int r = (u + 0x7FFFu + ((u >> 16) & 1u)) >> 16;   // RNE (finite inputs)
  return (unsigned short)r;
}
__device__ __forceinline__ float bf2f(unsigned short h) {
  return __uint_as_float(((unsigned int)h) << 16);
}

// Combined prep: blocks 0..63 pack W[512][256] -> MFMA B-fragment order hi/lo
// bf16 + row sum-squares; blocks 64..65 build VS/AP/G2 tables.
// frag elem (tile,step,lane,j) = src[tile*32+(lane&31)][step*16+8*(lane>>5)+j]
__global__ __launch_bounds__(256)
void prep(const float* __restrict__ Wsrc, const float* __restrict__ BETA,
          const float* __restrict__ alpha, const float* __restrict__ gamma,
          unsigned short* __restrict__ dh, unsigned short* __restrict__ dl,
          float* __restrict__ sq, float* __restrict__ VS,
          float* __restrict__ AP, float* __restrict__ G2)
{
  const int bid = blockIdx.x;
  if (bid < 64) {                      // ---- pack W ----
    const int tid = bid * 256 + threadIdx.x;
    const int row = tid >> 5, seg = tid & 31;
    const float4* s4 = (const float4*)(Wsrc + (size_t)row * ND + seg * 8);
    const float4 a = s4[0], b = s4[1];
    const float v[8] = {a.x, a.y, a.z, a.w, b.x, b.y, b.z, b.w};
    ushort8 hv, lv;
    float ssq = 0.f;
    #pragma unroll
    for (int j = 0; j < 8; ++j) {
      ssq = fmaf(v[j], v[j], ssq);
      const unsigned short hh = f2bf_rn(v[j]);
      hv[j] = hh;
      lv[j] = f2bf_rn(v[j] - bf2f(hh));
    }
    const int tile = row >> 5, m = row & 31, step = seg >> 1, r = seg & 1;
    const size_t cidx = (size_t)(tile * 16 + step) * 64 + m + 32 * r;
    *(ushort8*)(dh + cidx * 8) = hv;
    *(ushort8*)(dl + cidx * 8) = lv;
    #pragma unroll
    for (int off = 1; off < 32; off <<= 1) ssq += __shfl_xor(ssq, off, 64);
    if (seg == 0) sq[row] = ssq;
  } else {                             // ---- scalar tables ----
    const int k = (bid - 64) * 256 + threadIdx.x;
    if (k >= NP) return;
    float bv[NCLS], bs = 0.f;
    #pragma unroll
    for (int c = 0; c < NCLS; ++c) { bv[c] = BETA[k * NCLS + c]; bs = fmaf(bv[c], bv[c], bs); }
    const float binv = 1.f / bs;
    #pragma unroll
    for (int c = 0; c < NCLS; ++c) VS[c * NP + k] = 1.f - bv[c] * bv[c] * binv;
    VS[NCLS * NP + k] = 1.f;
    AP[k] = 0.99f / (1.f + __expf(-alpha[k]));
    const float g = gamma[k];
    G2[k] = g * g;
  }
}

// One MFMA pass over sample-half sh: 32x32 tile, K=256, hi/lo split in TWO
// acc chains (accA = ah*bh; accB = ah*bl + al*bh), DEPTH-8 B ring (~240cy
// prefetch ~ L2 latency; regs free at 1 block/CU), epilogue s -> sout[16].
__device__ __forceinline__ void mfma_pass8(
    const short* __restrict__ Ah, const short* __restrict__ Al,
    const short8* __restrict__ bHc, const short8* __restrict__ bLc,
    const int lane, const int sh, const float* __restrict__ xqs,
    const float wqk, const float apk, const float g2k, float* __restrict__ sout)
{
  short8 wbh[8], wbl[8];
  #pragma unroll
  for (int p = 0; p < 8; ++p) { wbh[p] = bHc[p * 64]; wbl[p] = bLc[p * 64]; }

  f32x16 accA, accB;
  #pragma unroll
  for (int i = 0; i < 16; ++i) { accA[i] = 0.f; accB[i] = 0.f; }
  const short8* aH = (const short8*)Ah + (size_t)sh * 1024 + lane;
  const short8* aL = (const short8*)Al + (size_t)sh * 1024 + lane;
  #pragma unroll
  for (int step = 0; step < 16; ++step) {
    const short8 ah = aH[step * 64], al = aL[step * 64];
    const short8 bh = wbh[step & 7], bl = wbl[step & 7];
    if (step < 8) {
      wbh[step & 7] = bHc[(step + 8) * 64];
      wbl[step & 7] = bLc[(step + 8) * 64];
    }
    accA = __builtin_amdgcn_mfma_f32_32x32x16_bf16(ah, bh, accA, 0, 0, 0);
    accB = __builtin_amdgcn_mfma_f32_32x32x16_bf16(ah, bl, accB, 0, 0, 0);
    accB = __builtin_amdgcn_mfma_f32_32x32x16_bf16(al, bh, accB, 0, 0, 0);
  }
  // C/D: col(n)=lane&31 (proto), row(m)=(rg&3)+8*(rg>>2)+4*(lane>>5)
  const int h = lane >> 5;
  #pragma unroll
  for (int rg = 0; rg < 16; ++rg) {
    const int   m  = (rg & 3) + 8 * (rg >> 2) + 4 * h;
    const float dv = 0.5f * (wqk + xqs[sh * 32 + m]) - (accA[rg] + accB[rg]);
    sout[rg] = apk * __expf(-g2k * dv);
  }
}

// ---- main: 256 blocks x 512 thr (1 block/CU). Block bx: samples bx*64..+64,
// ALL 512 protos in two phases, NO inter-phase barriers (per-wave
// self-contained s-tile bands + private VS slices). LDS: A-frags 64KB +
// sc[64][256] 64KB + vsl[8][20][32] 20KB + xqs; endgame aliases A after B5. ----
__global__ __launch_bounds__(512)
void evid64(const float* __restrict__ X,
            const unsigned short* __restrict__ PWH, const unsigned short* __restrict__ PWL,
            const float* __restrict__ VS, const float* __restrict__ WQ,
            const float* __restrict__ AP, const float* __restrict__ G2,
            float* __restrict__ OUT)
{
  __shared__ __align__(16) char pool[131072];
  __shared__ float vsl[8 * NCLS * 32];   // per-wave private VS slices (20KB)
  __shared__ float xqs[64];
  short* Ah = (short*)pool;            // 16384 shorts = 32KB
  short* Al = (short*)(pool + 32768);  // 16384 shorts = 32KB
  float* sc = (float*)(pool + 65536);  // 64 x 256 floats = 64KB (per phase)

  const int t    = threadIdx.x;
  const int lane = t & 63;
  const int wv   = __builtin_amdgcn_readfirstlane(t >> 6);  // wave 0..7
  const int bx   = blockIdx.x;
  const int bbase = bx * 64;
  const int pl = lane & 31, h = lane >> 5;

  // ---- stage: 64 X rows f32 -> hi/lo bf16 fragments (8 lanes/row, once) ----
  {
    const int r  = t >> 3;
    const int sg = t & 7;
    const int rsh = r >> 5, rm = r & 31;
    const float* xrow = X + (size_t)(bbase + r) * ND;
    float ssq = 0.f;
    #pragma unroll
    for (int it = 0; it < 8; ++it) {
      const int c0 = it * 32 + sg * 4;
      const float4 v = *(const float4*)(xrow + c0);
      const float vv[4] = {v.x, v.y, v.z, v.w};
      short4v h4, l4;
      #pragma unroll
      for (int j = 0; j < 4; ++j) {
        ssq = fmaf(vv[j], vv[j], ssq);
        const unsigned short hh = f2bf_rn(vv[j]);
        h4[j] = (short)hh;
        l4[j] = (short)f2bf_rn(vv[j] - bf2f(hh));
      }
      const int step = c0 >> 4, hf = (c0 >> 3) & 1, j0 = c0 & 7;
      const int base = (((rsh * 16 + step) * 64) + (rm + 32 * hf)) * 8 + j0;
      *(short4v*)&Ah[base] = h4;
      *(short4v*)&Al[base] = l4;
    }
    ssq += __shfl_xor(ssq, 1, 64);
    ssq += __shfl_xor(ssq, 2, 64);
    ssq += __shfl_xor(ssq, 4, 64);
    if (sg == 0) xqs[r] = ssq;
  }
  __syncthreads();                     // B1: A-frags + xqs ready

  float Apc[OC];
  #pragma unroll
  for (int c = 0; c < OC; ++c) Apc[c] = 1.0f;

  float* vw = vsl + wv * (NCLS * 32);  // this wave's private VS slice

  // ---- two proto-half phases; wave wv owns tile (ph*8 + wv). NO barriers:
  // s-band and VS slice are wave-private; waves free-run so one wave's
  // combine (VALU) overlaps another's MFMA + B-ring L2. ----
  #pragma unroll
  for (int ph = 0; ph < 2; ++ph) {
    // stage this wave's VS slice EARLY (hidden under the MFMA passes).
    // Single buffer is safe across phases: same-wave WAR via lgkmcnt.
    {
      const float* vg = VS + ph * 256 + wv * 32;     // + c*NP
      #pragma unroll
      for (int i = 0; i < 10; ++i) {
        const int idx = i * 64 + lane;               // 0..639 = c*32+j
        vw[idx] = vg[(idx >> 5) * NP + (idx & 31)];
      }
    }

    const int kp = ph * 256 + wv * 32 + pl;           // global proto id
    const float wqk = WQ[kp], apk = AP[kp], g2k = G2[kp];
    const short8* bHc = (const short8*)PWH + (size_t)(ph * 8 + wv) * 1024 + lane;
    const short8* bLc = (const short8*)PWL + (size_t)(ph * 8 + wv) * 1024 + lane;
    const int p = wv * 32 + pl;                       // proto within phase

    #pragma unroll
    for (int sh = 0; sh < 2; ++sh) {   // same B-tile both halves -> L1 reuse
      float sreg[16];
      mfma_pass8(Ah, Al, bHc, bLc, lane, sh, xqs, wqk, apk, g2k, sreg);
      #pragma unroll
      for (int rg = 0; rg < 16; ++rg) {
        const int m = (rg & 3) + 8 * (rg >> 2) + 4 * h;
        const int b = sh * 32 + m;
        sc[b * 256 + ((p + 4 * b) & 255)] = sreg[rg];  // own band only
      }
    }
    // no barrier: within-wave LDS write->read ordering via lgkmcnt

    // ---- combine: thread b = lane, own k-slice (wv). VS from LDS. ----
    {
      float sv[32];
      const int c0 = (wv * 32 + 4 * lane);
      #pragma unroll
      for (int q = 0; q < 8; ++q)
        *(float4*)&sv[4 * q] = *(const float4*)&sc[lane * 256 + ((c0 + 4 * q) & 255)];

      #pragma unroll 4
      for (int c = 0; c < NCLS; ++c) {
        const float* vp = vw + c * 32;                // LDS broadcast reads
        float f8[8];
        #pragma unroll
        for (int j = 0; j < 8; ++j) f8[j] = fmaf(-sv[j], vp[j], 1.0f);
        #pragma unroll
        for (int j = 8; j < 32; ++j) f8[j & 7] *= fmaf(-sv[j], vp[j], 1.0f);
        Apc[c] *= ((f8[0] * f8[1]) * (f8[2] * f8[3])) *
                  ((f8[4] * f8[5]) * (f8[6] * f8[7]));
      }
      // c = 20: VS row == 1.0 -> f = 1 - s
      {
        float f8[8];
        #pragma unroll
        for (int j = 0; j < 8; ++j) f8[j] = 1.0f - sv[j];
        #pragma unroll
        for (int j = 8; j < 32; ++j) f8[j & 7] *= (1.0f - sv[j]);
        Apc[NCLS] *= ((f8[0] * f8[1]) * (f8[2] * f8[3])) *
                     ((f8[4] * f8[5]) * (f8[6] * f8[7]));
      }
    }
  }
  __syncthreads();                     // B5: all waves done with A/sc regions

  // ---- endgame: reduce 8 wave-partials, normalize, store OUT in-block ----
  float* E  = (float*)pool;            // 8*21*64 floats = 42KB (A region, dead)
  float* R  = (float*)(pool + 43008);  // 21*64 floats
  float* kv = (float*)(pool + 48384);  // 64 floats
  #pragma unroll
  for (int c = 0; c < OC; ++c) E[(wv * OC + c) * 64 + lane] = Apc[c];
  __syncthreads();
  {
    const int b = t & 63, j = t >> 6;
    for (int c = j; c < OC; c += 8) {
      float p = E[c * 64 + b];
      #pragma unroll
      for (int w = 1; w < 8; ++w) p *= E[(w * OC + c) * 64 + b];
      R[c * 64 + b] = p;
    }
  }
  __syncthreads();
  if (t < 64) {
    const float Nv = R[NCLS * 64 + t];
    float K = Nv;
    #pragma unroll
    for (int c = 0; c < NCLS; ++c) K += R[c * 64 + t] - Nv;
    kv[t] = 1.0f / K;
  }
  __syncthreads();
  for (int idx = t; idx < 64 * OC; idx += 512) {
    const int b = idx / OC, c = idx - b * OC;
    const float Nv = R[NCLS * 64 + b];
    const float ik = kv[b];
    OUT[(size_t)bx * 64 * OC + idx] = (c < NCLS) ? (R[c * 64 + b] - Nv) * ik : Nv * ik;
  }
}

extern "C" void kernel_launch(void* const* d_in, const int* in_sizes, int n_in,
                              void* d_out, int out_size, void* d_ws, size_t ws_size,
                              hipStream_t stream) {
  (void)in_sizes; (void)n_in; (void)out_size; (void)ws_size;
  const float* X     = (const float*)d_in[0];
  const float* Wm    = (const float*)d_in[1];
  const float* BETA  = (const float*)d_in[2];
  const float* ALPHA = (const float*)d_in[3];
  const float* GAMMA = (const float*)d_in[4];
  float* OUT = (float*)d_out;

  char* ws = (char*)d_ws;
  unsigned short* PWH = (unsigned short*)(ws + OFF_PWH);
  unsigned short* PWL = (unsigned short*)(ws + OFF_PWL);
  float* VS = (float*)(ws + OFF_VS);
  float* WQ = (float*)(ws + OFF_WQ);
  float* AP = (float*)(ws + OFF_AP);
  float* G2 = (float*)(ws + OFF_G2);

  hipLaunchKernelGGL(prep, dim3(67 - 1), dim3(256), 0, stream,
                     Wm, BETA, ALPHA, GAMMA, PWH, PWL, WQ, VS, AP, G2);
  hipLaunchKernelGGL(evid64, dim3(NBATCH / 64), dim3(512), 0, stream,
                     X, PWH, PWL, VS, WQ, AP, G2, OUT);
}